// Round 8
// baseline (371.359 us; speedup 1.0000x reference)
//
#include <hip/hip_runtime.h>
#include <hip/hip_bf16.h>

#define CHN 256
#define PTS 9
#define LSZ 4096
#define MROWS 32768          // N*H*W
#define MI_TOT 2048          // MROWS/16

typedef unsigned short u16;
typedef __attribute__((ext_vector_type(4))) float f32x4;
typedef __attribute__((ext_vector_type(8))) short bf16x8;

// Split pair of f32 into packed bf16 hi/lo words (elem0 in low ushort).
__device__ __forceinline__ void split_pk(float a, float b, unsigned& hi, unsigned& lo) {
  float2 p; p.x = a; p.y = b;
  __hip_bfloat162 h = __float22bfloat162_rn(p);
  float2 r; r.x = a - __bfloat162float(h.x); r.y = b - __bfloat162float(h.y);
  __hip_bfloat162 l = __float22bfloat162_rn(r);
  hi = *reinterpret_cast<unsigned*>(&h);
  lo = *reinterpret_cast<unsigned*>(&l);
}

// async global->LDS, 16B per lane; LDS dest = uniform base + lane*16 (HW rule).
__device__ __forceinline__ void gl_lds16(const u16* g, u16* s) {
  __builtin_amdgcn_global_load_lds(
      (const __attribute__((address_space(1))) unsigned int*)(const void*)g,
      (__attribute__((address_space(3))) unsigned int*)(void*)s, 16, 0, 0);
}

// ---------------------------------------------------------------------------
// prep_x: x f32 [M][256] -> xh/xl bf16 in fragment-linear layout:
//   ushort idx = ((ks*MI_TOT + mi)*64 + slab*16 + lrow)*8 + e
//   (m = mi*16+lrow, k = ks*32 + slab*8 + e)
// Block = 16 rows (one mi). Two-phase LDS transpose, granule-XOR swizzled.
// ---------------------------------------------------------------------------
__global__ __launch_bounds__(256) void prep_x(const float* __restrict__ x,
    u16* __restrict__ xh, u16* __restrict__ xl) {
  __shared__ uint2 lh4[1024], ll4[1024];
  const int tid = threadIdx.x, b = blockIdx.x;
  const float4* src = (const float4*)(x + (size_t)b * 16 * 256);
#pragma unroll
  for (int j = 0; j < 4; ++j) {
    const int f4 = tid + j * 256;          // granule id: r*64 + c4
    const int r = f4 >> 6;
    float4 v = src[f4];
    unsigned h01, l01, h23, l23;
    split_pk(v.x, v.y, h01, l01);
    split_pk(v.z, v.w, h23, l23);
    const int gp = f4 ^ ((r & 7) << 1);    // bank-spread swizzle (bijective per row)
    uint2 hv; hv.x = h01; hv.y = h23;
    uint2 lv; lv.x = l01; lv.y = l23;
    lh4[gp] = hv; ll4[gp] = lv;
  }
  __syncthreads();
#pragma unroll
  for (int j = 0; j < 4; ++j) {
    const int flat = tid + j * 256;        // 1024 chunks of 16B (hi then lo)
    const int arr = flat >> 9, rem = flat & 511;
    const int ks = rem >> 6, lane = rem & 63;
    const int slab = lane >> 4, r = lane & 15;
    const int gA = r * 64 + ks * 8 + slab * 2;        // even
    const int gp = gA ^ ((r & 7) << 1);               // same swizzle
    const uint2* lsrc = arr ? ll4 : lh4;
    uint4 v = *(const uint4*)&lsrc[gp];
    u16* dst = arr ? xl : xh;
    *(uint4*)&dst[((size_t)(ks * MI_TOT + b) * 64 + lane) * 8] = v;
  }
}

// ---------------------------------------------------------------------------
// prep_w: weights -> fragment-linear packed B (B^T fragments):
//   ushort idx = ((ks*NI + ni)*64 + slab*16 + (n&15))*8 + e, k = 8*ko+e.
// Handles w_value (N=256), w_out (N=256), and [w_offset|w_mask|0] (N=128).
// ---------------------------------------------------------------------------
__global__ void prep_w(const float* __restrict__ wv, const float* __restrict__ wo,
    const float* __restrict__ woff, const float* __restrict__ wmsk,
    u16* __restrict__ pvh, u16* __restrict__ pvl,
    u16* __restrict__ poh, u16* __restrict__ pol,
    u16* __restrict__ pomh, u16* __restrict__ poml) {
  const int idx = blockIdx.x * 256 + threadIdx.x;   // 0..20479
  int n, ko, NI;
  u16 *dh, *dl;
  float vals[8];
  if (idx < 8192) {
    n = idx & 255; ko = idx >> 8; NI = 16; dh = pvh; dl = pvl;
#pragma unroll
    for (int e = 0; e < 8; ++e) vals[e] = wv[(size_t)(ko * 8 + e) * 256 + n];
  } else if (idx < 16384) {
    const int f = idx - 8192;
    n = f & 255; ko = f >> 8; NI = 16; dh = poh; dl = pol;
#pragma unroll
    for (int e = 0; e < 8; ++e) vals[e] = wo[(size_t)(ko * 8 + e) * 256 + n];
  } else {
    const int f = idx - 16384;
    n = f & 127; ko = f >> 7; NI = 8; dh = pomh; dl = poml;
#pragma unroll
    for (int e = 0; e < 8; ++e) {
      const int k = ko * 8 + e;
      vals[e] = (n < 72) ? woff[(size_t)k * 72 + n]
              : (n < 108 ? wmsk[(size_t)k * 36 + (n - 72)] : 0.f);
    }
  }
  const int ks = ko >> 2, slab = ko & 3, ni = n >> 4, lr = n & 15;
  uint4 hv, lv;
  split_pk(vals[0], vals[1], hv.x, lv.x);
  split_pk(vals[2], vals[3], hv.y, lv.y);
  split_pk(vals[4], vals[5], hv.z, lv.z);
  split_pk(vals[6], vals[7], hv.w, lv.w);
  const size_t d = ((size_t)(ks * NI + ni) * 64 + slab * 16 + lr) * 8;
  *(uint4*)&dh[d] = hv;
  *(uint4*)&dl[d] = lv;
}

// ---------------------------------------------------------------------------
// gemm_packed: C[M,N] = unpack(A)@unpack(B) + bias, A/B fragment-linear bf16
// hi/lo. BM=BN=128, BK=32, K=256 (8 steps). 4 waves (2x2), 64x64 per wave.
// Staging = global_load_lds dwordx4, linear LDS, conflict-free ds_read_b128.
// 3 MFMA per fragment pair (AhBh + AhBl + AlBh).
// ---------------------------------------------------------------------------
__global__ __launch_bounds__(256) void gemm_packed(
    const u16* __restrict__ Ah, const u16* __restrict__ Al,
    const u16* __restrict__ Bh, const u16* __restrict__ Bl,
    float* __restrict__ C, const float* __restrict__ b1, int s1,
    const float* __restrict__ b2, int s2, int N) {
  __shared__ u16 sAh[4096], sAl[4096], sBh[4096], sBl[4096];
  const int tid = threadIdx.x, lane = tid & 63, wid = tid >> 6;
  const int wr = wid >> 1, wc = wid & 1;
  const int lrow = lane & 15, slab = lane >> 4;
  const int mi0 = blockIdx.y * 8, ni0 = blockIdx.x * 8;
  const int NI = N >> 4;
  const int ft0 = wid * 2, ft1 = ft0 + 1;

  f32x4 acc[4][4] = {};

  for (int ks = 0; ks < 8; ++ks) {
    const size_t ab = ((size_t)(ks * MI_TOT + mi0) * 64 + lane) * 8;
    const size_t bb = ((size_t)(ks * NI + ni0) * 64 + lane) * 8;
    gl_lds16(Ah + ab + ft0 * 512, &sAh[ft0 * 512]);
    gl_lds16(Ah + ab + ft1 * 512, &sAh[ft1 * 512]);
    gl_lds16(Al + ab + ft0 * 512, &sAl[ft0 * 512]);
    gl_lds16(Al + ab + ft1 * 512, &sAl[ft1 * 512]);
    gl_lds16(Bh + bb + ft0 * 512, &sBh[ft0 * 512]);
    gl_lds16(Bh + bb + ft1 * 512, &sBh[ft1 * 512]);
    gl_lds16(Bl + bb + ft0 * 512, &sBl[ft0 * 512]);
    gl_lds16(Bl + bb + ft1 * 512, &sBl[ft1 * 512]);
    __syncthreads();   // drains vmcnt before ds_read

    bf16x8 a_h[4], a_l[4], b_h[4], b_l[4];
#pragma unroll
    for (int i = 0; i < 4; ++i) {
      a_h[i] = *(const bf16x8*)&sAh[(wr * 4 + i) * 512 + lane * 8];
      a_l[i] = *(const bf16x8*)&sAl[(wr * 4 + i) * 512 + lane * 8];
      b_h[i] = *(const bf16x8*)&sBh[(wc * 4 + i) * 512 + lane * 8];
      b_l[i] = *(const bf16x8*)&sBl[(wc * 4 + i) * 512 + lane * 8];
    }
#pragma unroll
    for (int m = 0; m < 4; ++m)
#pragma unroll
      for (int n = 0; n < 4; ++n) {
        acc[m][n] = __builtin_amdgcn_mfma_f32_16x16x32_bf16(a_h[m], b_h[n], acc[m][n], 0, 0, 0);
        acc[m][n] = __builtin_amdgcn_mfma_f32_16x16x32_bf16(a_h[m], b_l[n], acc[m][n], 0, 0, 0);
        acc[m][n] = __builtin_amdgcn_mfma_f32_16x16x32_bf16(a_l[m], b_h[n], acc[m][n], 0, 0, 0);
      }
    __syncthreads();
  }

  // C/D layout: col = lane&15, row = (lane>>4)*4 + reg (m89-verified, r4-passed)
  const int row0 = blockIdx.y * 128, col0 = blockIdx.x * 128;
#pragma unroll
  for (int m = 0; m < 4; ++m)
#pragma unroll
    for (int n = 0; n < 4; ++n) {
      const int col = col0 + wc * 64 + n * 16 + lrow;
      const float bv = (col < s1) ? b1[col] : (col < s2 ? b2[col - s1] : 0.f);
#pragma unroll
      for (int r = 0; r < 4; ++r) {
        const int row = row0 + wr * 64 + m * 16 + slab * 4 + r;
        C[(size_t)row * N + col] = acc[m][n][r] + bv;
      }
    }
}

// ---------------------------------------------------------------------------
// dcn_sample16: 1024 threads = 16 pixels, one wave per pixel (keeps 1024B
// contiguous gathers). lane>>4 = group, (lane&15)*4 = channel start.
// omv[M][128]: cols 0..71 offsets, 72..107 masks. Emits the out-GEMM's A
// directly as packed bf16 hi/lo (LDS repack -> coalesced 256B runs).
// Padded-coord algebra: px = w+1+dx+off_x on 66x66 zero-ring; corner counts
// iff inside [1,64]^2.
// ---------------------------------------------------------------------------
__global__ __launch_bounds__(1024, 8) void dcn_sample16(
    const float* __restrict__ val, const float* __restrict__ omv,
    u16* __restrict__ yh, u16* __restrict__ yl) {
  __shared__ float lom[16 * 128];
  __shared__ u16 lh[16 * 256], ll[16 * 256];
  const int tid = threadIdx.x;
  const int pix0 = blockIdx.x * 16;

  if (tid < 512)
    ((float4*)lom)[tid] = ((const float4*)(omv + (size_t)pix0 * 128))[tid];
  __syncthreads();

  const int wid = tid >> 6, lane = tid & 63;
  const int p = wid;
  const int pix = pix0 + p;
  const int n = pix >> 12, hw = pix & (LSZ - 1);
  const int h = hw >> 6, w = hw & 63;
  const int g = lane >> 4, cs = (lane & 15) << 2;

  const float* po = &lom[p * 128 + g * 18];
  const float* pm = &lom[p * 128 + 72 + g * 9];
  const float* vbase = val + (size_t)n * (LSZ * CHN) + g * 64 + cs;

  float4 acc = {0.f, 0.f, 0.f, 0.f};
#pragma unroll
  for (int pp = 0; pp < PTS; ++pp) {
    const int dx = pp / 3 - 1, dy = pp % 3 - 1;   // x-major flatten
    const float2 o = *(const float2*)&po[pp * 2];
    const float m = pm[pp];
    const float px = (float)(w + 1 + dx) + o.x;
    const float py = (float)(h + 1 + dy) + o.y;
    const float fx = floorf(px), fy = floorf(py);
    const int x0 = (int)fx, y0 = (int)fy;
    const float wx = px - fx, wy = py - fy;
    const float cw0 = m * (1.f - wx) * (1.f - wy);
    const float cw1 = m * wx * (1.f - wy);
    const float cw2 = m * (1.f - wx) * wy;
    const float cw3 = m * wx * wy;
#pragma unroll
    for (int c = 0; c < 4; ++c) {
      const int xi = x0 + (c & 1), yi = y0 + (c >> 1);
      const float cw = (c == 0) ? cw0 : (c == 1) ? cw1 : (c == 2) ? cw2 : cw3;
      const bool valid = (xi >= 1) & (xi <= 64) & (yi >= 1) & (yi <= 64);
      const int sx = min(max(xi - 1, 0), 63);
      const int sy = min(max(yi - 1, 0), 63);
      const float wgt = valid ? cw : 0.f;
      const float4 v = *(const float4*)&vbase[(size_t)(sy * 64 + sx) * CHN];
      acc.x += wgt * v.x; acc.y += wgt * v.y;
      acc.z += wgt * v.z; acc.w += wgt * v.w;
    }
  }

  // pack 4 channels -> hi/lo bf16, stage to LDS (granule-XOR on ch-granule)
  {
    unsigned h01, l01, h23, l23;
    split_pk(acc.x, acc.y, h01, l01);
    split_pk(acc.z, acc.w, h23, l23);
    const int gch = g * 8 + ((lane & 15) >> 1);   // (g*64+cs)>>3
    const int half = lane & 1;                    // (cs&4)>>2
    const int oidx = p * 256 + ((gch ^ (p & 7)) << 3) + (half << 2);
    uint2 hv; hv.x = h01; hv.y = h23;
    uint2 lv; lv.x = l01; lv.y = l23;
    *(uint2*)&lh[oidx] = hv;
    *(uint2*)&ll[oidx] = lv;
  }
  __syncthreads();

  // write out 1024 x 16B chunks, fragment-linear, coalesced 256B runs
  {
    const int arr = tid >> 9, rem = tid & 511;
    const int ks = rem >> 6, slab = (rem >> 4) & 3, pr = rem & 15;
    const int gr = ks * 4 + slab;
    const u16* ls = arr ? ll : lh;
    uint4 v = *(const uint4*)&ls[pr * 256 + ((gr ^ (pr & 7)) << 3)];
    u16* dst = arr ? yl : yh;
    const int mi = pix0 >> 4;
    *(uint4*)&dst[((size_t)(ks * MI_TOT + mi) * 64 + slab * 16 + pr) * 8] = v;
  }
}

extern "C" void kernel_launch(void* const* d_in, const int* in_sizes, int n_in,
                              void* d_out, int out_size, void* d_ws, size_t ws_size,
                              hipStream_t stream) {
  const float* x        = (const float*)d_in[0];
  const float* w_value  = (const float*)d_in[1];
  const float* b_value  = (const float*)d_in[2];
  const float* w_offset = (const float*)d_in[3];
  const float* b_offset = (const float*)d_in[4];
  const float* w_mask   = (const float*)d_in[5];
  const float* b_mask   = (const float*)d_in[6];
  const float* w_out    = (const float*)d_in[7];
  const float* b_out    = (const float*)d_in[8];
  float* out = (float*)d_out;

  char* p = (char*)d_ws;
  u16* xh    = (u16*)p;  p += (size_t)MROWS * 256 * 2;   // 16 MB
  u16* xl    = (u16*)p;  p += (size_t)MROWS * 256 * 2;   // 16 MB
  float* value = (float*)p; p += (size_t)MROWS * 256 * 4; // 32 MB
  float* omv   = (float*)p; p += (size_t)MROWS * 128 * 4; // 16 MB
  u16* yh    = (u16*)p;  p += (size_t)MROWS * 256 * 2;   // 16 MB
  u16* yl    = (u16*)p;  p += (size_t)MROWS * 256 * 2;   // 16 MB
  u16* pvh   = (u16*)p;  p += 131072;
  u16* pvl   = (u16*)p;  p += 131072;
  u16* poh   = (u16*)p;  p += 131072;
  u16* pol   = (u16*)p;  p += 131072;
  u16* pomh  = (u16*)p;  p += 65536;
  u16* poml  = (u16*)p;  p += 65536;

  prep_w<<<80, 256, 0, stream>>>(w_value, w_out, w_offset, w_mask,
                                 pvh, pvl, poh, pol, pomh, poml);
  prep_x<<<MI_TOT, 256, 0, stream>>>(x, xh, xl);
  // value GEMM: 32768 x 256 x 256
  gemm_packed<<<dim3(2, 256), 256, 0, stream>>>(
      xh, xl, pvh, pvl, value, b_value, 256, nullptr, 256, 256);
  // offset+mask GEMM: 32768 x 128 x 256 (cols 0..71 off, 72..107 msk, rest 0)
  gemm_packed<<<dim3(1, 256), 256, 0, stream>>>(
      xh, xl, pomh, poml, omv, b_offset, 72, b_mask, 108, 128);
  // sampling: 16 pixels/block, wave per pixel; emits packed bf16 A for out GEMM
  dcn_sample16<<<MROWS / 16, 1024, 0, stream>>>(value, omv, yh, yl);
  // output GEMM: 32768 x 256 x 256
  gemm_packed<<<dim3(2, 256), 256, 0, stream>>>(
      yh, yl, poh, pol, out, b_out, 256, nullptr, 256, 256);
}

// Round 12
// 213.472 us; speedup vs baseline: 1.7396x; 1.7396x over previous
//
#include <hip/hip_runtime.h>
#include <hip/hip_bf16.h>

#define CHN 256
#define PTS 9
#define LSZ 4096
#define MROWS 32768          // N*H*W
#define MI_TOT 2048          // MROWS/16

typedef unsigned short u16;
typedef __attribute__((ext_vector_type(4))) float f32x4;
typedef __attribute__((ext_vector_type(8))) short bf16x8;
typedef __attribute__((ext_vector_type(4))) unsigned int u32x4;

// Split pair of f32 into packed bf16 hi/lo words (elem0 in low ushort).
__device__ __forceinline__ void split_pk(float a, float b, unsigned& hi, unsigned& lo) {
  float2 p; p.x = a; p.y = b;
  __hip_bfloat162 h = __float22bfloat162_rn(p);
  float2 r; r.x = a - __bfloat162float(h.x); r.y = b - __bfloat162float(h.y);
  __hip_bfloat162 l = __float22bfloat162_rn(r);
  hi = *reinterpret_cast<unsigned*>(&h);
  lo = *reinterpret_cast<unsigned*>(&l);
}

// async global->LDS, 16B per lane; LDS dest = uniform base + lane*16 (HW rule).
__device__ __forceinline__ void gl_lds16(const u16* g, u16* s) {
  __builtin_amdgcn_global_load_lds(
      (const __attribute__((address_space(1))) unsigned int*)(const void*)g,
      (__attribute__((address_space(3))) unsigned int*)(void*)s, 16, 0, 0);
}

// ---------------------------------------------------------------------------
// prep_x: x f32 [M][256] -> xh/xl bf16 in fragment-linear layout:
//   ushort idx = ((ks*MI_TOT + mi)*64 + slab*16 + lrow)*8 + e
//   (m = mi*16+lrow, k = ks*32 + slab*8 + e)
// Block = 16 rows (one mi). Two-phase LDS transpose, granule-XOR swizzled.
// ---------------------------------------------------------------------------
__global__ __launch_bounds__(256) void prep_x(const float* __restrict__ x,
    u16* __restrict__ xh, u16* __restrict__ xl) {
  __shared__ uint2 lh4[1024], ll4[1024];
  const int tid = threadIdx.x, b = blockIdx.x;
  const float4* src = (const float4*)(x + (size_t)b * 16 * 256);
#pragma unroll
  for (int j = 0; j < 4; ++j) {
    const int f4 = tid + j * 256;          // granule id: r*64 + c4
    const int r = f4 >> 6;
    float4 v = src[f4];
    unsigned h01, l01, h23, l23;
    split_pk(v.x, v.y, h01, l01);
    split_pk(v.z, v.w, h23, l23);
    const int gp = f4 ^ ((r & 7) << 1);    // bank-spread swizzle (bijective per row)
    uint2 hv; hv.x = h01; hv.y = h23;
    uint2 lv; lv.x = l01; lv.y = l23;
    lh4[gp] = hv; ll4[gp] = lv;
  }
  __syncthreads();
#pragma unroll
  for (int j = 0; j < 4; ++j) {
    const int flat = tid + j * 256;        // 1024 chunks of 16B (hi then lo)
    const int arr = flat >> 9, rem = flat & 511;
    const int ks = rem >> 6, lane = rem & 63;
    const int slab = lane >> 4, r = lane & 15;
    const int gA = r * 64 + ks * 8 + slab * 2;        // even
    const int gp = gA ^ ((r & 7) << 1);               // same swizzle
    const uint2* lsrc = arr ? ll4 : lh4;
    uint4 v = *(const uint4*)&lsrc[gp];
    u16* dst = arr ? xl : xh;
    *(uint4*)&dst[((size_t)(ks * MI_TOT + b) * 64 + lane) * 8] = v;
  }
}

// ---------------------------------------------------------------------------
// prep_w: weights -> fragment-linear packed B (B^T fragments):
//   ushort idx = ((ks*NI + ni)*64 + slab*16 + (n&15))*8 + e, k = 8*ko+e.
// Handles w_value (N=256), w_out (N=256), and [w_offset|w_mask|0] (N=128).
// ---------------------------------------------------------------------------
__global__ void prep_w(const float* __restrict__ wv, const float* __restrict__ wo,
    const float* __restrict__ woff, const float* __restrict__ wmsk,
    u16* __restrict__ pvh, u16* __restrict__ pvl,
    u16* __restrict__ poh, u16* __restrict__ pol,
    u16* __restrict__ pomh, u16* __restrict__ poml) {
  const int idx = blockIdx.x * 256 + threadIdx.x;   // 0..20479
  int n, ko, NI;
  u16 *dh, *dl;
  float vals[8];
  if (idx < 8192) {
    n = idx & 255; ko = idx >> 8; NI = 16; dh = pvh; dl = pvl;
#pragma unroll
    for (int e = 0; e < 8; ++e) vals[e] = wv[(size_t)(ko * 8 + e) * 256 + n];
  } else if (idx < 16384) {
    const int f = idx - 8192;
    n = f & 255; ko = f >> 8; NI = 16; dh = poh; dl = pol;
#pragma unroll
    for (int e = 0; e < 8; ++e) vals[e] = wo[(size_t)(ko * 8 + e) * 256 + n];
  } else {
    const int f = idx - 16384;
    n = f & 127; ko = f >> 7; NI = 8; dh = pomh; dl = poml;
#pragma unroll
    for (int e = 0; e < 8; ++e) {
      const int k = ko * 8 + e;
      vals[e] = (n < 72) ? woff[(size_t)k * 72 + n]
              : (n < 108 ? wmsk[(size_t)k * 36 + (n - 72)] : 0.f);
    }
  }
  const int ks = ko >> 2, slab = ko & 3, ni = n >> 4, lr = n & 15;
  uint4 hv, lv;
  split_pk(vals[0], vals[1], hv.x, lv.x);
  split_pk(vals[2], vals[3], hv.y, lv.y);
  split_pk(vals[4], vals[5], hv.z, lv.z);
  split_pk(vals[6], vals[7], hv.w, lv.w);
  const size_t d = ((size_t)(ks * NI + ni) * 64 + slab * 16 + lr) * 8;
  *(uint4*)&dh[d] = hv;
  *(uint4*)&dl[d] = lv;
}

// ---------------------------------------------------------------------------
// gemm_packed: C[M,N] = unpack(A)@unpack(B) + bias, A/B fragment-linear bf16
// hi/lo. BM=BN=128, BK=32, K=256 (8 steps). 4 waves (2x2), 64x64 per wave.
// 2-PHASE double-buffered: issue next-tile global_load_lds BEFORE computing
// the current tile; single __syncthreads per tile (its vmcnt-drain is the
// exact wait for the prefetched tile, overlapped with ds_read+MFMA).
// 3 MFMA per fragment pair (AhBh + AhBl + AlBh).
// ---------------------------------------------------------------------------
__global__ __launch_bounds__(256) void gemm_packed(
    const u16* __restrict__ Ah, const u16* __restrict__ Al,
    const u16* __restrict__ Bh, const u16* __restrict__ Bl,
    float* __restrict__ C, const float* __restrict__ b1, int s1,
    const float* __restrict__ b2, int s2, int N) {
  __shared__ u16 sAh[2][4096], sAl[2][4096], sBh[2][4096], sBl[2][4096]; // 64 KB
  const int tid = threadIdx.x, lane = tid & 63, wid = tid >> 6;
  const int wr = wid >> 1, wc = wid & 1;
  const int lrow = lane & 15, slab = lane >> 4;
  const int mi0 = blockIdx.y * 8, ni0 = blockIdx.x * 8;
  const int NI = N >> 4;
  const int ft0 = wid * 2, ft1 = ft0 + 1;

  f32x4 acc[4][4] = {};

#define STAGE(buf, ksv) do {                                              \
    const size_t ab = ((size_t)((ksv) * MI_TOT + mi0) * 64 + lane) * 8;   \
    const size_t bb = ((size_t)((ksv) * NI + ni0) * 64 + lane) * 8;       \
    gl_lds16(Ah + ab + ft0 * 512, &sAh[buf][ft0 * 512]);                  \
    gl_lds16(Ah + ab + ft1 * 512, &sAh[buf][ft1 * 512]);                  \
    gl_lds16(Al + ab + ft0 * 512, &sAl[buf][ft0 * 512]);                  \
    gl_lds16(Al + ab + ft1 * 512, &sAl[buf][ft1 * 512]);                  \
    gl_lds16(Bh + bb + ft0 * 512, &sBh[buf][ft0 * 512]);                  \
    gl_lds16(Bh + bb + ft1 * 512, &sBh[buf][ft1 * 512]);                  \
    gl_lds16(Bl + bb + ft0 * 512, &sBl[buf][ft0 * 512]);                  \
    gl_lds16(Bl + bb + ft1 * 512, &sBl[buf][ft1 * 512]);                  \
  } while (0)

  STAGE(0, 0);
  __syncthreads();                        // tile 0 resident

  for (int ks = 0; ks < 8; ++ks) {
    const int cur = ks & 1;
    if (ks < 7) STAGE(cur ^ 1, ks + 1);   // prefetch next tile (overlaps below)

    bf16x8 a_h[4], a_l[4], b_h[4], b_l[4];
#pragma unroll
    for (int i = 0; i < 4; ++i) {
      a_h[i] = *(const bf16x8*)&sAh[cur][(wr * 4 + i) * 512 + lane * 8];
      a_l[i] = *(const bf16x8*)&sAl[cur][(wr * 4 + i) * 512 + lane * 8];
      b_h[i] = *(const bf16x8*)&sBh[cur][(wc * 4 + i) * 512 + lane * 8];
      b_l[i] = *(const bf16x8*)&sBl[cur][(wc * 4 + i) * 512 + lane * 8];
    }
#pragma unroll
    for (int m = 0; m < 4; ++m)
#pragma unroll
      for (int n = 0; n < 4; ++n) {
        acc[m][n] = __builtin_amdgcn_mfma_f32_16x16x32_bf16(a_h[m], b_h[n], acc[m][n], 0, 0, 0);
        acc[m][n] = __builtin_amdgcn_mfma_f32_16x16x32_bf16(a_h[m], b_l[n], acc[m][n], 0, 0, 0);
        acc[m][n] = __builtin_amdgcn_mfma_f32_16x16x32_bf16(a_l[m], b_h[n], acc[m][n], 0, 0, 0);
      }
    __syncthreads();   // next tile resident; buf[cur] free to overwrite
  }
#undef STAGE

  // C/D layout: col = lane&15, row = (lane>>4)*4 + reg (m89-verified, r4/r8-passed)
  const int row0 = blockIdx.y * 128, col0 = blockIdx.x * 128;
#pragma unroll
  for (int m = 0; m < 4; ++m)
#pragma unroll
    for (int n = 0; n < 4; ++n) {
      const int col = col0 + wc * 64 + n * 16 + lrow;
      const float bv = (col < s1) ? b1[col] : (col < s2 ? b2[col - s1] : 0.f);
#pragma unroll
      for (int r = 0; r < 4; ++r) {
        const int row = row0 + wr * 64 + m * 16 + slab * 4 + r;
        C[(size_t)row * N + col] = acc[m][n][r] + bv;
      }
    }
}

// ---------------------------------------------------------------------------
// dcn_sample16: 1024 threads = 16 pixels, one wave per pixel.
// XCD-aware block swizzle: grid 2048 = 8 XCDs x 256 blocks; each XCD gets one
// contiguous image (4 MB value slice = its whole L2) -> 36-tap window reuse
// becomes L2-local instead of cross-XCD thrash (r8: FETCH 401 MB vs 48 MB
// compulsory). omv is streamed via nontemporal loads; yh/yl stores are
// nontemporal (write-once) so neither evicts the value lines.
// Padded-coord algebra: px = w+1+dx+off_x on 66x66 zero-ring; corner counts
// iff inside [1,64]^2.
// ---------------------------------------------------------------------------
__global__ __launch_bounds__(1024) void dcn_sample16(
    const float* __restrict__ val, const float* __restrict__ omv,
    u16* __restrict__ yh, u16* __restrict__ yl) {
  __shared__ float lom[16 * 128];
  __shared__ u16 lh[16 * 256], ll[16 * 256];
  const int tid = threadIdx.x;
  const int bswz = ((blockIdx.x & 7) << 8) + (blockIdx.x >> 3);  // image-per-XCD
  const int pix0 = bswz * 16;

  if (tid < 512) {
    u32x4 v = __builtin_nontemporal_load(
        (const u32x4*)(omv + (size_t)pix0 * 128) + tid);
    ((u32x4*)lom)[tid] = v;
  }
  __syncthreads();

  const int wid = tid >> 6, lane = tid & 63;
  const int p = wid;
  const int pix = pix0 + p;
  const int n = pix >> 12, hw = pix & (LSZ - 1);
  const int h = hw >> 6, w = hw & 63;
  const int g = lane >> 4, cs = (lane & 15) << 2;

  const float* po = &lom[p * 128 + g * 18];
  const float* pm = &lom[p * 128 + 72 + g * 9];
  const float* vbase = val + (size_t)n * (LSZ * CHN) + g * 64 + cs;

  float4 acc = {0.f, 0.f, 0.f, 0.f};
#pragma unroll
  for (int pp = 0; pp < PTS; ++pp) {
    const int dx = pp / 3 - 1, dy = pp % 3 - 1;   // x-major flatten
    const float2 o = *(const float2*)&po[pp * 2];
    const float m = pm[pp];
    const float px = (float)(w + 1 + dx) + o.x;
    const float py = (float)(h + 1 + dy) + o.y;
    const float fx = floorf(px), fy = floorf(py);
    const int x0 = (int)fx, y0 = (int)fy;
    const float wx = px - fx, wy = py - fy;
    const float cw0 = m * (1.f - wx) * (1.f - wy);
    const float cw1 = m * wx * (1.f - wy);
    const float cw2 = m * (1.f - wx) * wy;
    const float cw3 = m * wx * wy;
#pragma unroll
    for (int c = 0; c < 4; ++c) {
      const int xi = x0 + (c & 1), yi = y0 + (c >> 1);
      const float cw = (c == 0) ? cw0 : (c == 1) ? cw1 : (c == 2) ? cw2 : cw3;
      const bool valid = (xi >= 1) & (xi <= 64) & (yi >= 1) & (yi <= 64);
      const int sx = min(max(xi - 1, 0), 63);
      const int sy = min(max(yi - 1, 0), 63);
      const float wgt = valid ? cw : 0.f;
      const float4 v = *(const float4*)&vbase[(size_t)(sy * 64 + sx) * CHN];
      acc.x += wgt * v.x; acc.y += wgt * v.y;
      acc.z += wgt * v.z; acc.w += wgt * v.w;
    }
  }

  // pack 4 channels -> hi/lo bf16, stage to LDS (granule-XOR on ch-granule)
  {
    unsigned h01, l01, h23, l23;
    split_pk(acc.x, acc.y, h01, l01);
    split_pk(acc.z, acc.w, h23, l23);
    const int gch = g * 8 + ((lane & 15) >> 1);   // (g*64+cs)>>3
    const int half = lane & 1;                    // (cs&4)>>2
    const int oidx = p * 256 + ((gch ^ (p & 7)) << 3) + (half << 2);
    uint2 hv; hv.x = h01; hv.y = h23;
    uint2 lv; lv.x = l01; lv.y = l23;
    *(uint2*)&lh[oidx] = hv;
    *(uint2*)&ll[oidx] = lv;
  }
  __syncthreads();

  // write out 1024 x 16B chunks, fragment-linear, coalesced 256B runs (nt)
  {
    const int arr = tid >> 9, rem = tid & 511;
    const int ks = rem >> 6, slab = (rem >> 4) & 3, pr = rem & 15;
    const int gr = ks * 4 + slab;
    const u16* ls = arr ? ll : lh;
    u32x4 v = *(const u32x4*)&ls[pr * 256 + ((gr ^ (pr & 7)) << 3)];
    u16* dst = arr ? yl : yh;
    const int mi = pix0 >> 4;
    __builtin_nontemporal_store(v,
        (u32x4*)&dst[((size_t)(ks * MI_TOT + mi) * 64 + slab * 16 + pr) * 8]);
  }
}

extern "C" void kernel_launch(void* const* d_in, const int* in_sizes, int n_in,
                              void* d_out, int out_size, void* d_ws, size_t ws_size,
                              hipStream_t stream) {
  const float* x        = (const float*)d_in[0];
  const float* w_value  = (const float*)d_in[1];
  const float* b_value  = (const float*)d_in[2];
  const float* w_offset = (const float*)d_in[3];
  const float* b_offset = (const float*)d_in[4];
  const float* w_mask   = (const float*)d_in[5];
  const float* b_mask   = (const float*)d_in[6];
  const float* w_out    = (const float*)d_in[7];
  const float* b_out    = (const float*)d_in[8];
  float* out = (float*)d_out;

  char* p = (char*)d_ws;
  u16* xh    = (u16*)p;  p += (size_t)MROWS * 256 * 2;   // 16 MB
  u16* xl    = (u16*)p;  p += (size_t)MROWS * 256 * 2;   // 16 MB
  float* value = (float*)p; p += (size_t)MROWS * 256 * 4; // 32 MB
  float* omv   = (float*)p; p += (size_t)MROWS * 128 * 4; // 16 MB
  u16* yh    = (u16*)p;  p += (size_t)MROWS * 256 * 2;   // 16 MB
  u16* yl    = (u16*)p;  p += (size_t)MROWS * 256 * 2;   // 16 MB
  u16* pvh   = (u16*)p;  p += 131072;
  u16* pvl   = (u16*)p;  p += 131072;
  u16* poh   = (u16*)p;  p += 131072;
  u16* pol   = (u16*)p;  p += 131072;
  u16* pomh  = (u16*)p;  p += 65536;
  u16* poml  = (u16*)p;  p += 65536;

  prep_w<<<80, 256, 0, stream>>>(w_value, w_out, w_offset, w_mask,
                                 pvh, pvl, poh, pol, pomh, poml);
  prep_x<<<MI_TOT, 256, 0, stream>>>(x, xh, xl);
  // value GEMM: 32768 x 256 x 256
  gemm_packed<<<dim3(2, 256), 256, 0, stream>>>(
      xh, xl, pvh, pvl, value, b_value, 256, nullptr, 256, 256);
  // offset+mask GEMM: 32768 x 128 x 256 (cols 0..71 off, 72..107 msk, rest 0)
  gemm_packed<<<dim3(1, 256), 256, 0, stream>>>(
      xh, xl, pomh, poml, omv, b_offset, 72, b_mask, 108, 128);
  // sampling: 16 pixels/block, wave per pixel; XCD-swizzled, emits packed A
  dcn_sample16<<<MROWS / 16, 1024, 0, stream>>>(value, omv, yh, yl);
  // output GEMM: 32768 x 256 x 256
  gemm_packed<<<dim3(2, 256), 256, 0, stream>>>(
      yh, yl, poh, pol, out, b_out, 256, nullptr, 256, 256);
}